// Round 3
// baseline (125.680 us; speedup 1.0000x reference)
//
#include <hip/hip_runtime.h>
#include <math.h>

#define Bn   128
#define Rn   1152
#define CIn  8
#define Cn   10
#define On   16
#define BO   2048      // Bn*On
#define CBO  20480     // Cn*BO
#define RC   12        // r's per wave-segment
#define NSEG 96        // 96*12 = 1152
#define PSEG 24        // wg-level partial segments (4 waves reduced per wg)

// ---- transpose x[b][r][i] -> XT[r][g][b][q]  (i = g*4+q), float4 units
__global__ __launch_bounds__(256)
void transpose_x(const float* __restrict__ X, float* __restrict__ XT)
{
    const int r = blockIdx.x;
    const int b = threadIdx.x & 127;
    const int g = threadIdx.x >> 7;
    float4 v = *(const float4*)(X + (size_t)b * (Rn * CIn) + r * CIn + g * 4);
    ((float4*)XT)[r * 256 + g * 128 + b] = v;
}

// ---- pass kernel: W staged in LDS (vector path), broadcast ds_read in loop.
// wg(256) = 4 waves; wave sw covers (c, bh, seg = segq*4+sw), rows r0..r0+11.
// Block W span: rows segq*48 .. segq*48+47 of channel c = 24KB, staged once.
// lane = local b (0..63); thread owns all 16 o's.
// Grid: 480 = Cn(10) * 2 bh * 24 segq ; 3 blocks/CU resident -> whole grid resident
template<int PASS>
__global__ __launch_bounds__(256, 3)
void pass_kernel(const float* __restrict__ XT, const float* __restrict__ W,
                 const float* __restrict__ Sprev, const float* __restrict__ N2,
                 float* __restrict__ PT, float* __restrict__ PL)
{
    // 34.8 KB shared: W tile [48][128] (24KB) during main loop,
    // then reduction buffer [4][64][34] (34.8KB) after a barrier.
    __shared__ __align__(16) float smem[4 * 64 * 34];
    float (*wlds)[128] = (float (*)[128])smem;
    float (*red)[64][34] = (float (*)[64][34])smem;

    const int blk  = blockIdx.x;
    const int c    = blk / 48;
    const int rem  = blk - c * 48;
    const int bh   = rem / 24;
    const int segq = rem - bh * 24;
    const int tid  = threadIdx.x;
    const int w    = tid >> 6;
    const int lane = tid & 63;
    const int b    = bh * 64 + lane;

    // ---- stage W tile: 48 rows * 128 floats = 1536 float4, coalesced
    {
        const float4* gw4 = (const float4*)(W + (size_t)(c * Rn + segq * 48) * 128);
        float4* sw4 = (float4*)&wlds[0][0];
        #pragma unroll
        for (int k = 0; k < 6; ++k)
            sw4[tid + k * 256] = gw4[tid + k * 256];
    }

    // per-thread Vsum (pre-scaled by log2e) from previous passes
    float vs[16];
    if (PASS > 1) {
        float coef[PASS];
        #pragma unroll
        for (int t = 0; t < PASS - 1; ++t) {
            const float n2 = N2[t];
            coef[t] = n2 / ((1.0f + n2) * sqrtf(n2)) * 1.4426950408889634f;
        }
        const float* sp = Sprev + c * BO + b * On;
        #pragma unroll
        for (int q = 0; q < 4; ++q) {
            float4 a = make_float4(0.f, 0.f, 0.f, 0.f);
            #pragma unroll
            for (int t = 0; t < PASS - 1; ++t) {
                const float4 s4 = *(const float4*)(sp + t * CBO + q * 4);
                a.x = fmaf(coef[t], s4.x, a.x);
                a.y = fmaf(coef[t], s4.y, a.y);
                a.z = fmaf(coef[t], s4.z, a.z);
                a.w = fmaf(coef[t], s4.w, a.w);
            }
            vs[q * 4 + 0] = a.x; vs[q * 4 + 1] = a.y;
            vs[q * 4 + 2] = a.z; vs[q * 4 + 3] = a.w;
        }
    }

    float tacc[16], lacc[16];
    #pragma unroll
    for (int o = 0; o < 16; ++o) { tacc[o] = 0.0f; lacc[o] = 0.0f; }

    __syncthreads();   // W tile visible to all waves

    const float4* XT4 = (const float4*)XT;
    for (int rr = 0; rr < RC; ++rr) {
        const int lrow = w * RC + rr;           // LDS row (wave-uniform)
        const int r    = segq * 48 + lrow;      // global r
        const float4 xa = XT4[r * 256 + b];
        const float4 xb = XT4[r * 256 + 128 + b];
        const float xi[8] = { xa.x, xa.y, xa.z, xa.w, xb.x, xb.y, xb.z, xb.w };

        float u[16];
        #pragma unroll
        for (int o = 0; o < 16; ++o) u[o] = 0.0f;
        #pragma unroll
        for (int i = 0; i < 8; ++i) {
            // 16 consecutive floats, wave-uniform address -> 4x ds_read_b128 broadcast
            const float4 w0 = *(const float4*)&wlds[lrow][i * 16 + 0];
            const float4 w1 = *(const float4*)&wlds[lrow][i * 16 + 4];
            const float4 w2 = *(const float4*)&wlds[lrow][i * 16 + 8];
            const float4 w3 = *(const float4*)&wlds[lrow][i * 16 + 12];
            const float x = xi[i];
            u[0]  = fmaf(x, w0.x, u[0]);  u[1]  = fmaf(x, w0.y, u[1]);
            u[2]  = fmaf(x, w0.z, u[2]);  u[3]  = fmaf(x, w0.w, u[3]);
            u[4]  = fmaf(x, w1.x, u[4]);  u[5]  = fmaf(x, w1.y, u[5]);
            u[6]  = fmaf(x, w1.z, u[6]);  u[7]  = fmaf(x, w1.w, u[7]);
            u[8]  = fmaf(x, w2.x, u[8]);  u[9]  = fmaf(x, w2.y, u[9]);
            u[10] = fmaf(x, w2.z, u[10]); u[11] = fmaf(x, w2.w, u[11]);
            u[12] = fmaf(x, w3.x, u[12]); u[13] = fmaf(x, w3.y, u[13]);
            u[14] = fmaf(x, w3.z, u[14]); u[15] = fmaf(x, w3.w, u[15]);
        }
        #pragma unroll
        for (int o = 0; o < 16; ++o) {
            if (PASS == 1) {
                tacc[o] += u[o];
            } else {
                const float e = exp2f(u[o] * vs[o]);
                lacc[o] += e;
                tacc[o] = fmaf(e, u[o], tacc[o]);
            }
        }
    }

    __syncthreads();   // all waves done reading wlds; smem becomes red

    #pragma unroll
    for (int o = 0; o < 16; ++o) {
        red[w][lane][o]      = tacc[o];
        red[w][lane][16 + o] = lacc[o];
    }
    __syncthreads();

    {
        const int bl = tid >> 2;          // 0..63
        const int og = tid & 3;           // 0..3
        const int bg = bh * 64 + bl;
        float4 tv, lv;
        float* tp = (float*)&tv;
        float* lp = (float*)&lv;
        #pragma unroll
        for (int q = 0; q < 4; ++q) {
            const int o = og * 4 + q;
            tp[q] = red[0][bl][o] + red[1][bl][o] + red[2][bl][o] + red[3][bl][o];
            lp[q] = red[0][bl][16 + o] + red[1][bl][16 + o] +
                    red[2][bl][16 + o] + red[3][bl][16 + o];
        }
        const int idx = segq * CBO + c * BO + bg * On + og * 4;
        *(float4*)(PT + idx) = tv;
        if (PASS > 1) *(float4*)(PL + idx) = lv;
    }
}

// sum partials over PSEG segs; s = T/L; store S slot; reduce sum(s^2) -> N2 slot
template<int PASS>
__global__ __launch_bounds__(256)
void combine_kernel(const float* __restrict__ PT, const float* __restrict__ PL,
                    float* __restrict__ Sout, float* __restrict__ n2out)
{
    const int i = blockIdx.x * 256 + threadIdx.x;   // 80 blocks * 256 = 20480
    float T = 0.0f, L = 0.0f;
    #pragma unroll
    for (int s = 0; s < PSEG; ++s) T += PT[s * CBO + i];
    if (PASS == 1) {
        L = (float)Rn;
    } else {
        #pragma unroll
        for (int s = 0; s < PSEG; ++s) L += PL[s * CBO + i];
    }
    const float sv = T / L;
    Sout[i] = sv;
    float sq = sv * sv;
    #pragma unroll
    for (int d = 1; d < 64; d <<= 1) sq += __shfl_xor(sq, d);
    __shared__ float red[4];
    if ((threadIdx.x & 63) == 0) red[threadIdx.x >> 6] = sq;
    __syncthreads();
    if (threadIdx.x == 0)
        atomicAdd(n2out, red[0] + red[1] + red[2] + red[3]);
}

__global__ __launch_bounds__(256)
void final_kernel(const float* __restrict__ S, const float* __restrict__ n2p,
                  float* __restrict__ out)
{
    const int i = blockIdx.x * 256 + threadIdx.x;
    const float n2 = *n2p;
    const float coef = n2 / ((1.0f + n2) * sqrtf(n2));
    out[i] = coef * S[i];
}

extern "C" void kernel_launch(void* const* d_in, const int* in_sizes, int n_in,
                              void* d_out, int out_size, void* d_ws, size_t ws_size,
                              hipStream_t stream)
{
    const float* X = (const float*)d_in[0];
    const float* W = (const float*)d_in[1];
    float* ws = (float*)d_ws;
    float* XT = ws;                          // 1,179,648 floats (4.7 MB)
    float* N2 = XT + Rn * Bn * CIn;          // 4 floats
    float* PT = N2 + 4;                      // PSEG*CBO = 491,520
    float* PL = PT + PSEG * CBO;             // PSEG*CBO
    float* S  = PL + PSEG * CBO;             // 3*CBO

    hipMemsetAsync(N2, 0, 16, stream);       // zero n^2 accumulators only

    transpose_x<<<Rn, 256, 0, stream>>>(X, XT);
    pass_kernel<1><<<480, 256, 0, stream>>>(XT, W, S, N2, PT, PL);
    combine_kernel<1><<<80, 256, 0, stream>>>(PT, PL, S + 0 * CBO, N2 + 0);
    pass_kernel<2><<<480, 256, 0, stream>>>(XT, W, S, N2, PT, PL);
    combine_kernel<2><<<80, 256, 0, stream>>>(PT, PL, S + 1 * CBO, N2 + 1);
    pass_kernel<3><<<480, 256, 0, stream>>>(XT, W, S, N2, PT, PL);
    combine_kernel<3><<<80, 256, 0, stream>>>(PT, PL, S + 2 * CBO, N2 + 2);
    final_kernel<<<80, 256, 0, stream>>>(S + 2 * CBO, N2 + 2, (float*)d_out);
}